// Round 5
// baseline (10.612 us; speedup 1.0000x reference)
//
#include <hip/hip_runtime.h>

#define IN_  1024
#define OUT_ 1024

typedef _Float16 f16x8 __attribute__((ext_vector_type(8)));
typedef float    f32x4 __attribute__((ext_vector_type(4)));

// Block = 32 m-rows x 16 n-cols (both GEMMs). grid 256 = 4 mq x 64 g.
// 512 thr = 8 waves; within a 256-wide K-chunk, wave w computes k-sub [w*32,+32).
// LDS: two 32KB chunk buffers (sA 16KB + sB 16KB each); reduction reuses buf0.
// All 4 chunks' global loads issued up-front (single HBM latency exposure).
__global__ __launch_bounds__(512, 1) void dendritic_fused(
    const float* __restrict__ x,   // [128,1024]
    const float* __restrict__ Wn,  // [1024,1024]
    const float* __restrict__ Wo,  // [1024,1024]
    const float* __restrict__ bo,  // [1024]
    float* __restrict__ out) {     // [128,1024]
  __shared__ __align__(16) char lds[65536];

  const int tid = threadIdx.x;
  const int w   = tid >> 6;
  const int l   = tid & 63;
  const int g   = blockIdx.x & 63;   // W-sharing blocks (same g): b%8==g%8 -> co-XCD
  const int mq  = blockIdx.x >> 6;
  const int m0  = mq * 32;
  const int n0  = g * 16;

  // staging geometry: unit i=0..3 is a 16-row band (x lo, x hi, Wn, Wo); 8 f32/thread
  const int c8  = tid & 31;          // 8-float column chunk within 256-wide K-chunk
  const int rb  = tid >> 5;          // row within band 0..15
  const int swz = (rb & 7) << 4;
  const float* srcrow0 = x  + (size_t)(m0 + rb)      * IN_ + c8 * 8;
  const float* srcrow1 = x  + (size_t)(m0 + 16 + rb) * IN_ + c8 * 8;
  const float* srcrow2 = Wn + (size_t)(n0 + rb)      * IN_ + c8 * 8;
  const float* srcrow3 = Wo + (size_t)(n0 + rb)      * IN_ + c8 * 8;
  const int d0 = rb * 512                + ((c8 * 16) ^ swz);
  const int d1 = (16 + rb) * 512         + ((c8 * 16) ^ swz);
  const int d2 = 16384 + rb * 512        + ((c8 * 16) ^ swz);
  const int d3 = 16384 + 8192 + rb * 512 + ((c8 * 16) ^ swz);

  float4 v0[4][2], v1[4][2], v2[4][2], v3[4][2];

#define LOADC(vv, ch) do {                                                \
    const float4* p0 = (const float4*)(srcrow0 + (ch) * 256);             \
    const float4* p1 = (const float4*)(srcrow1 + (ch) * 256);             \
    const float4* p2 = (const float4*)(srcrow2 + (ch) * 256);             \
    const float4* p3 = (const float4*)(srcrow3 + (ch) * 256);             \
    vv[0][0] = p0[0]; vv[0][1] = p0[1];                                   \
    vv[1][0] = p1[0]; vv[1][1] = p1[1];                                   \
    vv[2][0] = p2[0]; vv[2][1] = p2[1];                                   \
    vv[3][0] = p3[0]; vv[3][1] = p3[1];                                   \
  } while (0)

#define WRITEC(vv, ch, bb) do {                                           \
    _Pragma("unroll")                                                     \
    for (int i = 0; i < 4; ++i) {                                         \
      f16x8 h = { (_Float16)vv[i][0].x, (_Float16)vv[i][0].y,             \
                  (_Float16)vv[i][0].z, (_Float16)vv[i][0].w,             \
                  (_Float16)vv[i][1].x, (_Float16)vv[i][1].y,             \
                  (_Float16)vv[i][1].z, (_Float16)vv[i][1].w };           \
      if (i == 2) { /* fold conv edges: halve Wn col 0 / col 1023 */      \
        if ((ch) == 0 && c8 == 0)  h[0] = h[0] * (_Float16)0.5f;          \
        if ((ch) == 3 && c8 == 31) h[7] = h[7] * (_Float16)0.5f;          \
      }                                                                   \
      const int dd = (i == 0 ? d0 : i == 1 ? d1 : i == 2 ? d2 : d3);      \
      *(f16x8*)(lds + (bb) + dd) = h;                                     \
    }                                                                     \
  } while (0)

  // compute-fragment LDS offsets (same swizzle as staging)
  const int fr = l & 15;
  const int cb = ((w * 64 + (l >> 4) * 16) ^ ((fr & 7) << 4));
  const int o_a0 = fr * 512 + cb;
  const int o_a1 = (16 + fr) * 512 + cb;
  const int o_bn = 16384 + fr * 512 + cb;
  const int o_bw = 16384 + 8192 + fr * 512 + cb;

  f32x4 acc00 = {0.f,0.f,0.f,0.f}, acc01 = {0.f,0.f,0.f,0.f};
  f32x4 acc10 = {0.f,0.f,0.f,0.f}, acc11 = {0.f,0.f,0.f,0.f};

#define COMPUTE(bb) do {                                                  \
    f16x8 a0 = *(const f16x8*)(lds + (bb) + o_a0);                        \
    f16x8 a1 = *(const f16x8*)(lds + (bb) + o_a1);                        \
    f16x8 bn = *(const f16x8*)(lds + (bb) + o_bn);                        \
    f16x8 bw = *(const f16x8*)(lds + (bb) + o_bw);                        \
    acc00 = __builtin_amdgcn_mfma_f32_16x16x32_f16(a0, bn, acc00, 0,0,0); \
    acc01 = __builtin_amdgcn_mfma_f32_16x16x32_f16(a0, bw, acc01, 0,0,0); \
    acc10 = __builtin_amdgcn_mfma_f32_16x16x32_f16(a1, bn, acc10, 0,0,0); \
    acc11 = __builtin_amdgcn_mfma_f32_16x16x32_f16(a1, bw, acc11, 0,0,0); \
  } while (0)

  // ---- issue ALL global loads up-front: one latency exposure ----
  LOADC(v0, 0);
  LOADC(v1, 1);
  LOADC(v2, 2);
  LOADC(v3, 3);

  WRITEC(v0, 0, 0);
  __syncthreads();              // buf0 ready
  COMPUTE(0);
  WRITEC(v1, 1, 32768);
  __syncthreads();              // buf1 ready; buf0 readers done
  COMPUTE(32768);
  WRITEC(v2, 2, 0);
  __syncthreads();              // buf0 ready; buf1 readers done
  COMPUTE(0);
  WRITEC(v3, 3, 32768);
  __syncthreads();              // buf1 ready; buf0 readers done
  COMPUTE(32768);

  // ---- K-reduction (reuse buf0 region) + fused epilogue ----
  *(f32x4*)(lds + (((w * 2 + 0) * 2 + 0) * 64 + l) * 16) = acc00;
  *(f32x4*)(lds + (((w * 2 + 0) * 2 + 1) * 64 + l) * 16) = acc01;
  *(f32x4*)(lds + (((w * 2 + 1) * 2 + 0) * 64 + l) * 16) = acc10;
  *(f32x4*)(lds + (((w * 2 + 1) * 2 + 1) * 64 + l) * 16) = acc11;
  __syncthreads();

  if (tid < 128) {
    const int mt = tid >> 6;
    const int ll = tid & 63;
    f32x4 sN = {0.f,0.f,0.f,0.f}, sO = {0.f,0.f,0.f,0.f};
#pragma unroll
    for (int q = 0; q < 8; ++q) {
      sN += *(const f32x4*)(lds + (((q * 2 + mt) * 2 + 0) * 64 + ll) * 16);
      sO += *(const f32x4*)(lds + (((q * 2 + mt) * 2 + 1) * 64 + ll) * 16);
    }
    const int n = n0 + (ll & 15);
    const float bias = bo[n];
#pragma unroll
    for (int r = 0; r < 4; ++r) {
      const int m = m0 + mt * 16 + (ll >> 4) * 4 + r;
      const float zN = sN[r];                              // edges pre-folded
      const float zO = sO[r] + bias;
      const float state = 1.f / (1.f + expf(-zO)) - 1.f;   // (-1,0)
      const float nm    = 2.f + state;                     // (1,2)
      const float kd    = exp2f(-nm);                      // 0.5^nm
      const float ca    = fmaxf(zN, 0.f);
      const float xn    = (ca > 0.f) ? exp2f(nm * log2f(ca)) : 0.f;
      out[(size_t)m * OUT_ + n] = xn / (kd + xn) + state;
    }
  }
#undef LOADC
#undef WRITEC
#undef COMPUTE
}

extern "C" void kernel_launch(void* const* d_in, const int* in_sizes, int n_in,
                              void* d_out, int out_size, void* d_ws, size_t ws_size,
                              hipStream_t stream) {
  const float* x  = (const float*)d_in[0];
  const float* Wn = (const float*)d_in[1];
  const float* Wo = (const float*)d_in[2];
  const float* bo = (const float*)d_in[3];
  float* out = (float*)d_out;
  dendritic_fused<<<dim3(256), dim3(512), 0, stream>>>(x, Wn, Wo, bo, out);
}